// Round 1
// baseline (6329.988 us; speedup 1.0000x reference)
//
#include <hip/hip_runtime.h>
#include <cstdint>
#include <cstddef>

#define B_  32
#define T_  64
#define D_  512
#define H_  512
#define V_  32000
#define GATES 2048

// ---------------- module-global scratch ---------------------------------------
__device__ float g_h[2][2 * B_ * H_];        // ping-pong [slot][layer*B*H]
__device__ float g_c[2][2 * B_ * H_];
__device__ int   g_fin[2][B_];               // finished flag, ping-pong by t&1
__device__ unsigned long long g_best[B_];    // packed (orderedVal<<32)|(~v)
__device__ float g_wT[512 * 32000];          // fc_w^T  [k][v]
__device__ float g_wLT[2][1024 * 2048];      // per layer [k][gate*512+j], k=[x;h]
__device__ float g_part0[16][B_][GATES];     // L0 partials: 16 x 64-k slices
__device__ float g_part1[24][B_][GATES];     // L1: x slots 0..15 (32-k), h slots 16..23 (64-k)
__device__ float g_lpart[4][B_][V_];         // logits k-split partials (128-k slices)

// ---------------- Threefry-2x32 (20 rounds), exact JAX schedule ----------------
__host__ __device__ __forceinline__ void threefry2x32(uint32_t k0, uint32_t k1,
                                                      uint32_t x0, uint32_t x1,
                                                      uint32_t& o0, uint32_t& o1) {
  uint32_t kx = k0 ^ k1 ^ 0x1BD11BDAu;
  x0 += k0; x1 += k1;
#define RND(r) { x0 += x1; x1 = (x1 << (r)) | (x1 >> (32 - (r))); x1 ^= x0; }
  RND(13) RND(15) RND(26) RND(6)  x0 += k1; x1 += kx + 1u;
  RND(17) RND(29) RND(16) RND(24) x0 += kx; x1 += k0 + 2u;
  RND(13) RND(15) RND(26) RND(6)  x0 += k0; x1 += k1 + 3u;
  RND(17) RND(29) RND(16) RND(24) x0 += k1; x1 += kx + 4u;
  RND(13) RND(15) RND(26) RND(6)  x0 += kx; x1 += k0 + 5u;
#undef RND
  o0 = x0; o1 = x1;
}

__device__ __forceinline__ float gumbel_from_u32(uint32_t bits) {
  float f = __uint_as_float((bits >> 9) | 0x3f800000u) - 1.0f;   // [0,1)
  const float TINY = 1.1754943508222875e-38f;
  float u = f * (1.0f - TINY) + TINY;
  u = fmaxf(u, TINY);
  return -logf(-logf(u));
}

// ---------------- init ---------------------------------------------------------
__global__ void init_kernel(const float* __restrict__ h_enc,
                            const float* __restrict__ c_enc) {
  int i = blockIdx.x * 256 + threadIdx.x;
  if (i < 2 * B_ * H_) { g_h[0][i] = h_enc[i]; g_c[0][i] = c_enc[i]; }
  if (i < B_) { g_fin[0][i] = 0; g_fin[1][i] = 0; }
}

// ---------------- one-time weight transpose (64x64 LDS-tiled, coalesced) -------
__global__ void transpose_kernel(const float* __restrict__ src, int R, int which) {
  float* dst;
  switch (which) {
    case 0:  dst = g_wT; break;
    case 1:  dst = g_wLT[0]; break;
    case 2:  dst = g_wLT[0] + 512 * 2048; break;
    case 3:  dst = g_wLT[1]; break;
    default: dst = g_wLT[1] + 512 * 2048; break;
  }
  __shared__ float tile[64][65];
  const int r0 = blockIdx.x * 64;
  const int c0 = blockIdx.y * 64;
  const int tx = threadIdx.x & 63;
  const int ty = threadIdx.x >> 6;          // 0..3
#pragma unroll
  for (int i = 0; i < 16; ++i) {
    const int row = ty + 4 * i;
    tile[row][tx] = src[(size_t)(r0 + row) * 512 + c0 + tx];
  }
  __syncthreads();
#pragma unroll
  for (int i = 0; i < 16; ++i) {
    const int row = ty + 4 * i;
    dst[(size_t)(c0 + row) * R + r0 + tx] = tile[tx][row];
  }
}

// ---------------- helpers ------------------------------------------------------
// Stage PER floats per thread from row[...] into transposed LDS zs[k][32].
template<int PER>
__device__ __forceinline__ void stage_t(float* __restrict__ zs,
                                        const float* __restrict__ row,
                                        int kq, int b) {
#pragma unroll
  for (int i = 0; i < PER; i += 4) {
    const float4 v = *(const float4*)&row[kq * PER + i];
    const int kk = kq * PER + i;
    zs[(kk + 0) * 32 + b] = v.x;
    zs[(kk + 1) * 32 + b] = v.y;
    zs[(kk + 2) * 32 + b] = v.z;
    zs[(kk + 3) * 32 + b] = v.w;
  }
}

// Gate-matmul partial: thread owns 2 gate-columns (j0+2*tid), all 32 b, KS k's.
// wrow points at weight row k0 (layout [k][2048]); zs is LDS [KS][32].
template<int KS>
__device__ __forceinline__ void mm_part(const float* __restrict__ wrow,
                                        float* __restrict__ pout,   // [32][2048]
                                        const float* __restrict__ zs,
                                        int j0, int tid) {
  float2 acc[32];
#pragma unroll
  for (int b = 0; b < 32; ++b) acc[b] = make_float2(0.f, 0.f);
#pragma unroll 4
  for (int k = 0; k < KS; ++k) {
    const float2 w = *(const float2*)&wrow[(size_t)k * GATES + j0 + 2 * tid];
    const float4* z4 = (const float4*)&zs[k * 32];
#pragma unroll
    for (int bq = 0; bq < 8; ++bq) {
      const float4 z = z4[bq];
      acc[bq * 4 + 0].x += w.x * z.x; acc[bq * 4 + 0].y += w.y * z.x;
      acc[bq * 4 + 1].x += w.x * z.y; acc[bq * 4 + 1].y += w.y * z.y;
      acc[bq * 4 + 2].x += w.x * z.z; acc[bq * 4 + 2].y += w.y * z.z;
      acc[bq * 4 + 3].x += w.x * z.w; acc[bq * 4 + 3].y += w.y * z.w;
    }
  }
#pragma unroll
  for (int b = 0; b < 32; ++b)
    *(float2*)&pout[(size_t)b * GATES + j0 + 2 * tid] = acc[b];
}

__device__ __forceinline__ int unpack_v(unsigned long long bb) {
  int v = (int)(0xFFFFFFFFu - (uint32_t)(bb & 0xFFFFFFFFu));
  if (v < 0) v = 0;
  if (v >= V_) v = V_ - 1;
  return v;
}

// ---------------- K1: L0 full gates partial + L1 h-part partial ----------------
// grid 96. blocks 0..63: L0 (ks=blk>>2 in 0..15, 64-k slices over [x;h0]).
// blocks 64..95: L1 h-part (ks 0..7, 64-k slices over h1_prev -> slots 16+ks).
// Also: consumes previous step's argmax (g_best) -> token, fin, out_tokens,
// and gathers embed[token] directly into the LDS z-tile (x source).
__global__ void parts_a_kernel(int cur, int t,
                               const float* __restrict__ input_seq,
                               const float* __restrict__ embed,
                               float* __restrict__ out_tokens) {
  __shared__ __align__(16) float zs[64 * 32];
  __shared__ int stok[B_];
  const int tid = threadIdx.x;
  const int blk = blockIdx.x;
  const int b = tid >> 3, kq = tid & 7;

  if (blk < 64) {
    const int ks = blk >> 2, jt = blk & 3;
    const int k0 = ks * 64, j0 = jt * 512;
    if (k0 < 512) {
      // ---- x source ----
      if (t == 0) {
        const float* row = &input_seq[(size_t)b * (T_ * D_)];   // input_seq[b][0][:]
        stage_t<8>(zs, row + k0, kq, b);
      } else {
        if (tid < B_) {
          unsigned long long bb = g_best[tid];
          int v = unpack_v(bb);
          int fin = g_fin[(t + 1) & 1][tid];       // fin_{t-1}
          int tok = fin ? 0 : v;                   // PAD=0
          stok[tid] = tok;
          if (blk == 0) {
            out_tokens[(size_t)tid * T_ + (t - 1)] = (float)tok;
            g_fin[t & 1][tid] = fin | (v == 3 ? 1 : 0);   // EOS=3
          }
        }
        __syncthreads();
        const float* row = &embed[(size_t)stok[b] * D_];
        stage_t<8>(zs, row + k0, kq, b);
      }
    } else {
      // ---- h0_prev source ----
      const float* row = &g_h[cur][0 * B_ * H_ + b * H_];
      stage_t<8>(zs, row + (k0 - 512), kq, b);
    }
    __syncthreads();
    mm_part<64>(&g_wLT[0][(size_t)k0 * GATES], &g_part0[ks][0][0], zs, j0, tid);
  } else {
    const int bb2 = blk - 64;
    const int ks = bb2 >> 2, jt = bb2 & 3;
    const int k0 = ks * 64, j0 = jt * 512;
    const float* row = &g_h[cur][1 * B_ * H_ + b * H_];          // h1_prev
    stage_t<8>(zs, row + k0, kq, b);
    __syncthreads();
    mm_part<64>(&g_wLT[1][(size_t)(512 + k0) * GATES], &g_part1[16 + ks][0][0],
                zs, j0, tid);
  }
}

// ---------------- K3: L1 x-part (h0_new @ Wih1^T), ks 0..15 (32-k slices) ------
__global__ void parts_l1x_kernel(int cur) {
  __shared__ __align__(16) float zs[32 * 32];
  const int tid = threadIdx.x;
  const int ks = blockIdx.x >> 2, jt = blockIdx.x & 3;
  const int k0 = ks * 32, j0 = jt * 512;
  const int b = tid >> 3, kq = tid & 7;
  const float* row = &g_h[cur ^ 1][0 * B_ * H_ + b * H_];        // h0 new
  stage_t<4>(zs, row + k0, kq, b);
  __syncthreads();
  mm_part<32>(&g_wLT[1][(size_t)k0 * GATES], &g_part1[ks][0][0], zs, j0, tid);
}

// ---------------- finish: sum slots (ascending) + activations ------------------
// grid 64 x 256; gid = b*512 + j
__global__ void lstm_finish_kernel(int cur, int layer, int nslots,
                                   const float* __restrict__ bih,
                                   const float* __restrict__ bhh) {
  const int gid = blockIdx.x * 256 + threadIdx.x;
  const int b = gid >> 9, j = gid & 511;
  const float* P = (layer == 0) ? &g_part0[0][0][0] : &g_part1[0][0][0];
  float gi = 0.f, gf = 0.f, gg = 0.f, go = 0.f;
  for (int s = 0; s < nslots; ++s) {
    const float* p = P + (size_t)s * B_ * GATES + (size_t)b * GATES;
    gi += p[j];
    gf += p[512 + j];
    gg += p[1024 + j];
    go += p[1536 + j];
  }
  gi += bih[j]        + bhh[j];
  gf += bih[512 + j]  + bhh[512 + j];
  gg += bih[1024 + j] + bhh[1024 + j];
  go += bih[1536 + j] + bhh[1536 + j];

  const float* c_in = &g_c[cur][layer * B_ * H_];
  float* h_out = &g_h[cur ^ 1][layer * B_ * H_];
  float* c_out = &g_c[cur ^ 1][layer * B_ * H_];
  float c0 = c_in[b * H_ + j];
  float si = 1.f / (1.f + expf(-gi));
  float sf = 1.f / (1.f + expf(-gf));
  float so = 1.f / (1.f + expf(-go));
  float cn = sf * c0 + si * tanhf(gg);
  float hn = so * tanhf(cn);
  c_out[b * H_ + j] = cn;
  h_out[b * H_ + j] = hn;
}

// ---------------- K5: logits partial, ks4 x vt63, wT read-once -----------------
// block: 512 v (thread owns 2) x 32 b x 128 k. h1 staged transposed in LDS.
__global__ void logits_part_kernel(int cur) {
  __shared__ __align__(16) float hs[128 * 32];   // 16 KB [k][b]
  const int blk = blockIdx.x;
  const int vt = blk % 63, ks = blk / 63;        // ks 0..3
  const int tid = threadIdx.x;
  const int k0 = ks * 128;

  if (blk == 0 && tid < B_) g_best[tid] = 0ull;  // reset before K6's atomicMax

  {
    const int b = tid >> 3, kq = tid & 7;        // 16 floats per thread
    const float* row = &g_h[cur ^ 1][B_ * H_ + b * H_];
    stage_t<16>(hs, row + k0, kq, b);
  }
  __syncthreads();

  const int v0 = vt * 512 + tid * 2;
  if (v0 >= V_) return;                          // tail guard (vt=62 upper lanes)

  float2 acc[32];
#pragma unroll
  for (int b = 0; b < 32; ++b) acc[b] = make_float2(0.f, 0.f);
#pragma unroll 4
  for (int k = 0; k < 128; ++k) {
    const float2 w = *(const float2*)&g_wT[(size_t)(k0 + k) * V_ + v0];
    const float4* z4 = (const float4*)&hs[k * 32];
#pragma unroll
    for (int bq = 0; bq < 8; ++bq) {
      const float4 z = z4[bq];
      acc[bq * 4 + 0].x += w.x * z.x; acc[bq * 4 + 0].y += w.y * z.x;
      acc[bq * 4 + 1].x += w.x * z.y; acc[bq * 4 + 1].y += w.y * z.y;
      acc[bq * 4 + 2].x += w.x * z.z; acc[bq * 4 + 2].y += w.y * z.z;
      acc[bq * 4 + 3].x += w.x * z.w; acc[bq * 4 + 3].y += w.y * z.w;
    }
  }
#pragma unroll
  for (int b = 0; b < 32; ++b)
    *(float2*)&g_lpart[ks][b][v0] = acc[b];
}

// ---------------- K6: combine + gumbel + per-b argmax via packed atomicMax -----
// grid 256 = b(32) x vr(8, 4000 v each); 256 thr.
__global__ void logits_combine_kernel(const float* __restrict__ fc_b,
                                      float* __restrict__ out_logits,
                                      int t, uint32_t key0, uint32_t key1) {
  __shared__ unsigned long long sv[256];
  const int b  = blockIdx.x >> 3;
  const int vr = blockIdx.x & 7;
  const int tid = threadIdx.x;
  const int vend = (vr + 1) * 4000;

  unsigned long long best = 0ull;
  for (int it = 0; it < 16; ++it) {
    const int v = vr * 4000 + it * 256 + tid;
    if (v < vend) {
      float s = g_lpart[0][b][v] + g_lpart[1][b][v]
              + g_lpart[2][b][v] + g_lpart[3][b][v];
      float lv = s + fc_b[v];
      out_logits[(size_t)(b * T_ + t) * V_ + v] = lv;
      uint32_t y0, y1;
      threefry2x32(key0, key1, 0u, (uint32_t)(b * V_ + v), y0, y1);
      float val = lv + gumbel_from_u32(y0 ^ y1);
      uint32_t u = __float_as_uint(val);
      u ^= (u >> 31) ? 0xFFFFFFFFu : 0x80000000u;            // ordered-float map
      unsigned long long pk =
          ((unsigned long long)u << 32) | (unsigned long long)(0xFFFFFFFFu - (uint32_t)v);
      if (pk > best) best = pk;                               // tie -> smaller v
    }
  }
  sv[tid] = best;
  __syncthreads();
  for (int s = 128; s > 0; s >>= 1) {
    if (tid < s) { if (sv[tid + s] > sv[tid]) sv[tid] = sv[tid + s]; }
    __syncthreads();
  }
  if (tid == 0) atomicMax(&g_best[b], sv[0]);
}

// ---------------- epilogue: finalize token for t = T-1 -------------------------
__global__ void finalize_kernel(float* __restrict__ out_tokens) {
  const int tid = threadIdx.x;
  if (tid < B_) {
    int v = unpack_v(g_best[tid]);
    int fin = g_fin[(T_ + 1) & 1][tid];          // fin_{T-1}
    int tok = fin ? 0 : v;
    out_tokens[(size_t)tid * T_ + (T_ - 1)] = (float)tok;
  }
}

// ---------------- host driver -------------------------------------------------
extern "C" void kernel_launch(void* const* d_in, const int* in_sizes, int n_in,
                              void* d_out, int out_size, void* d_ws, size_t ws_size,
                              hipStream_t stream) {
  const float* input_seq = (const float*)d_in[0];
  const float* h_enc = (const float*)d_in[1];
  const float* c_enc = (const float*)d_in[2];
  const float* Wih   = (const float*)d_in[3];
  const float* Whh   = (const float*)d_in[4];
  const float* bih   = (const float*)d_in[5];
  const float* bhh   = (const float*)d_in[6];
  const float* fc_w  = (const float*)d_in[7];
  const float* fc_b  = (const float*)d_in[8];
  const float* embed = (const float*)d_in[9];
  float* out = (float*)d_out;
  float* tok_out = out + (size_t)B_ * T_ * V_;
  (void)d_ws; (void)ws_size; (void)in_sizes; (void)n_in; (void)out_size;

  init_kernel<<<128, 256, 0, stream>>>(h_enc, c_enc);

  transpose_kernel<<<dim3(500, 8), 256, 0, stream>>>(fc_w, 32000, 0);
  transpose_kernel<<<dim3(32, 8),  256, 0, stream>>>(Wih,                      2048, 1);
  transpose_kernel<<<dim3(32, 8),  256, 0, stream>>>(Whh,                      2048, 2);
  transpose_kernel<<<dim3(32, 8),  256, 0, stream>>>(Wih + (size_t)2048 * 512, 2048, 3);
  transpose_kernel<<<dim3(32, 8),  256, 0, stream>>>(Whh + (size_t)2048 * 512, 2048, 4);

  uint32_t keys[T_][2];
  for (int t = 0; t < T_; ++t)
    threefry2x32(0u, 42u, 0u, (uint32_t)t, keys[t][0], keys[t][1]);

  int cur = 0;
  for (int t = 0; t < T_; ++t) {
    parts_a_kernel<<<96, 256, 0, stream>>>(cur, t, input_seq, embed, tok_out);
    lstm_finish_kernel<<<64, 256, 0, stream>>>(cur, 0, 16, bih, bhh);
    parts_l1x_kernel<<<64, 256, 0, stream>>>(cur);
    lstm_finish_kernel<<<64, 256, 0, stream>>>(cur, 1, 24, bih + 2048, bhh + 2048);
    logits_part_kernel<<<252, 256, 0, stream>>>(cur);
    logits_combine_kernel<<<256, 256, 0, stream>>>(fc_b, out, t, keys[t][0], keys[t][1]);
    cur ^= 1;
  }
  finalize_kernel<<<1, 64, 0, stream>>>(tok_out);
}